// Round 1
// 102.442 us; speedup vs baseline: 1.0350x; 1.0350x over previous
//
#include <hip/hip_runtime.h>

#define N_NODES 100000
#define N_EDGES 1000000
#define D 64
#define N_GRAPHS 512
#define DOT_THREADS (N_NODES * 16)        // 16 threads per node
#define DOT_BLOCKS (DOT_THREADS / 256)    // 6250, exact
#define TAIL_BLOCKS 4                     // 4 blocks x 128 graphs
#define K2_THREADS 1024
#define K2_BLOCKS ((N_EDGES / 4 + K2_THREADS - 1) / K2_THREADS)  // 245

// K1: y[v] = dot(x[v,:], W)  (16 threads/node, float4 each — wave reads a
//     fully-contiguous 1 KiB span: 4 nodes x 256 B).
//     + 4 tail blocks hidden under the 25.6 MB x-stream:
//       ONE binary search per thread (lower_bound shared via LDS with the
//       t+1 neighbor -> dependent-load chain halved vs 2 searches/thread),
//       writes inv_cnt[g] and seeds out[g] = b (K3 eliminated).
__global__ __launch_bounds__(256) void dot_kernel(const float* __restrict__ x,
                                                  const float* __restrict__ W,
                                                  const int* __restrict__ batch,
                                                  const float* __restrict__ bptr,
                                                  float* __restrict__ y,
                                                  float* __restrict__ inv_cnt,
                                                  float* __restrict__ out) {
    __shared__ int slb[132];   // 129 used; dot blocks never touch it
    if (blockIdx.x < DOT_BLOCKS) {
        int t = blockIdx.x * 256 + threadIdx.x;
        int v = t >> 4;      // node index
        int sub = t & 15;    // 16 sub-lanes cover 64 floats via float4
        const float4 xv = *reinterpret_cast<const float4*>(x + (size_t)v * D + sub * 4);
        const float4 wv = *reinterpret_cast<const float4*>(W + sub * 4);
        float p = xv.x * wv.x + xv.y * wv.y + xv.z * wv.z + xv.w * wv.w;
        p += __shfl_xor(p, 1, 64);
        p += __shfl_xor(p, 2, 64);
        p += __shfl_xor(p, 4, 64);
        p += __shfl_xor(p, 8, 64);
        if (sub == 0) y[v] = p;
        return;
    }
    // tail block tb covers graphs [tb*128, tb*128+128)
    const int tb = blockIdx.x - DOT_BLOCKS;
    const int gbase = tb * 128;
    const int t = threadIdx.x;
    if (t <= 128) {
        // slb[t] = lower_bound(batch, gbase + t) — 17 dependent loads, L2-warm
        const int target = gbase + t;
        int lo = 0, hi = N_NODES;
        while (lo < hi) {
            int mid = (lo + hi) >> 1;
            if (batch[mid] < target) lo = mid + 1; else hi = mid;
        }
        slb[t] = lo;
    }
    __syncthreads();
    if (t < 128) {
        const int g = gbase + t;
        float cnt = (float)(slb[t + 1] - slb[t]);
        inv_cnt[g] = 1.0f / fmaxf(cnt, 1.0f);
        out[g] = bptr[0];    // seed with bias; K2 atomically accumulates
    }
}

// K2: per-block LDS histogram of edge_attr[e]*y[src_e] into graph bins;
//     flush applies inv_cnt scaling and adds STRAIGHT INTO out (no K3).
//     NO fences/counters — device-scope fence machinery cost 76 us in a
//     previous round.
__global__ __launch_bounds__(K2_THREADS) void edge_kernel(const int* __restrict__ ei,
                                                          const float* __restrict__ ea,
                                                          const int* __restrict__ batch,
                                                          const float* __restrict__ y,
                                                          const float* __restrict__ inv_cnt,
                                                          float* __restrict__ out) {
    __shared__ float sacc[N_GRAPHS];
    const int tid = threadIdx.x;
    if (tid < N_GRAPHS) sacc[tid] = 0.0f;
    __syncthreads();

    // 4 edges per thread via 16B loads; 250000 vec-edges over 245x1024 threads
    int idx = blockIdx.x * K2_THREADS + tid;
    if (idx < N_EDGES / 4) {
        const int4   s4 = reinterpret_cast<const int4*>(ei)[idx];
        const int4   d4 = reinterpret_cast<const int4*>(ei + N_EDGES)[idx];
        const float4 a4 = reinterpret_cast<const float4*>(ea)[idx];
        // 4 independent gather pairs -> ILP hides L2 latency
        float m0 = a4.x * y[s4.x];  int g0 = batch[d4.x];
        float m1 = a4.y * y[s4.y];  int g1 = batch[d4.y];
        float m2 = a4.z * y[s4.z];  int g2 = batch[d4.z];
        float m3 = a4.w * y[s4.w];  int g3 = batch[d4.w];
        atomicAdd(&sacc[g0], m0);
        atomicAdd(&sacc[g1], m1);
        atomicAdd(&sacc[g2], m2);
        atomicAdd(&sacc[g3], m3);
    }
    __syncthreads();
    if (tid < N_GRAPHS) {
        float v = sacc[tid];
        if (v != 0.0f) atomicAdd(&out[tid], v * inv_cnt[tid]);
    }
}

extern "C" void kernel_launch(void* const* d_in, const int* in_sizes, int n_in,
                              void* d_out, int out_size, void* d_ws, size_t ws_size,
                              hipStream_t stream) {
    const float* x     = (const float*)d_in[0];  // [N, 64] fp32
    const int*   ei    = (const int*)  d_in[1];  // [2, E] int32
    const float* ea    = (const float*)d_in[2];  // [E] fp32
    const int*   batch = (const int*)  d_in[3];  // [N] int32, sorted
    const float* W     = (const float*)d_in[4];  // [1, 64] fp32
    const float* b     = (const float*)d_in[5];  // [1] fp32
    float* out = (float*)d_out;                  // [G, 1] = 512 fp32

    float* y       = (float*)d_ws;               // N_NODES floats
    float* inv_cnt = y + N_NODES;                // N_GRAPHS floats

    // K1: 6250 dot blocks + 4 tail blocks (inv_cnt + out=b seed)
    dot_kernel<<<DOT_BLOCKS + TAIL_BLOCKS, 256, 0, stream>>>(
        x, W, batch, b, y, inv_cnt, out);
    // K2: 245 blocks x 1024 threads, accumulates scaled sums into out
    edge_kernel<<<K2_BLOCKS, K2_THREADS, 0, stream>>>(ei, ea, batch, y, inv_cnt, out);
}